// Round 4
// baseline (893.408 us; speedup 1.0000x reference)
//
#include <hip/hip_runtime.h>

#define CDIM 128
#define C3   384
#define NLAYER 3
#define BROWS 32     // rows per GRU block
#define GROWS 8      // rows per gather block

typedef __attribute__((ext_vector_type(8))) __bf16 bf16x8;
typedef __attribute__((ext_vector_type(4))) __bf16 bf16x4;
typedef __attribute__((ext_vector_type(4))) float  f32x4;
typedef __attribute__((ext_vector_type(4))) unsigned short u16x4;

static __device__ __forceinline__ f32x4 mfma16(bf16x8 a, bf16x8 b, f32x4 c) {
    return __builtin_amdgcn_mfma_f32_16x16x32_bf16(a, b, c, 0, 0, 0);
}

// async global->LDS, 16B per lane; LDS dest = uniform base + lane*16
static __device__ __forceinline__ void load_lds16(const float* g, float* l) {
    __builtin_amdgcn_global_load_lds(
        (const __attribute__((address_space(1))) unsigned int*)(const void*)g,
        (__attribute__((address_space(3))) unsigned int*)(void*)l,
        16, 0, 0);
}

// f32 -> packed (bf16_hi << 16) | bf16_lo  with lo = v - hi
static __device__ __forceinline__ unsigned int packf(float v) {
    __bf16 h = (__bf16)v;
    __bf16 l = (__bf16)(v - (float)h);
    unsigned short hb, lb;
    __builtin_memcpy(&hb, &h, 2);
    __builtin_memcpy(&lb, &l, 2);
    return ((unsigned int)hb << 16) | lb;
}

// ---------------------------------------------------------------------------
// prep 1: wT[j][c] = w_ih[c][j]
// ---------------------------------------------------------------------------
__global__ __launch_bounds__(256) void prep_transpose(const float* __restrict__ w_ih,
                                                      float* __restrict__ wT) {
    int idx = blockIdx.x * 256 + threadIdx.x;       // 128*384
    int j = idx / C3, c = idx % C3;
    wT[idx] = w_ih[c * CDIM + j];
}

// ---------------------------------------------------------------------------
// prep 2: Wc[l][p][c] = sum_j W[l][p][j] * w_ih[c][j]
// ---------------------------------------------------------------------------
__global__ __launch_bounds__(256) void prep_wc(const float* __restrict__ weight,
                                               const float* __restrict__ wT,
                                               float* __restrict__ Wc) {
    __shared__ float wrow[CDIM];
    const int b = blockIdx.x;                        // l*128 + p
    if (threadIdx.x < CDIM) wrow[threadIdx.x] = weight[(size_t)b * CDIM + threadIdx.x];
    __syncthreads();
    for (int c = threadIdx.x; c < C3; c += 256) {
        float acc = 0.f;
        #pragma unroll 8
        for (int j = 0; j < CDIM; ++j) acc = fmaf(wrow[j], wT[j * C3 + c], acc);
        Wc[(size_t)b * C3 + c] = acc;
    }
}

// ---------------------------------------------------------------------------
// prep 3: pack V[256][512] (= [s_r | s_z | i_n | h_n]) into MFMA fragment
// order, bf16 hi/lo.  frag(kt,ct): lane l, j -> V[kt*32+(l>>4)*8+j][ct*16+(l&15)]
// ---------------------------------------------------------------------------
__global__ __launch_bounds__(256) void prep_pack(const float* __restrict__ Wc,
                                                 const float* __restrict__ w_hh,
                                                 __bf16* __restrict__ vfh,
                                                 __bf16* __restrict__ vfl) {
    const int fid  = blockIdx.x * 4 + (threadIdx.x >> 6);   // 0..767 = l*256 + kt*32 + ct
    const int lane = threadIdx.x & 63;
    const int l    = fid >> 8;
    const int rem  = fid & 255;
    const int kt   = rem >> 5, ct = rem & 31;
    const int kbase = kt * 32 + (lane >> 4) * 8;
    const int c     = ct * 16 + (lane & 15);

    bf16x8 H, L;
    #pragma unroll
    for (int j = 0; j < 8; ++j) {
        int k = kbase + j;
        float v;
        if (k < CDIM) {
            v = (c < C3) ? Wc[((size_t)l * CDIM + k) * C3 + c] : 0.f;
        } else {
            int q = k - CDIM;
            if (c < 256)      v = w_hh[(size_t)c * CDIM + q];          // r,z rows
            else if (c < C3)  v = 0.f;                                  // i_n: no h part
            else              v = w_hh[(size_t)(c - CDIM) * CDIM + q];  // n rows 256..383
        }
        __bf16 h = (__bf16)v;
        H[j] = h;
        L[j] = (__bf16)(v - (float)h);
    }
    size_t base = ((size_t)fid * 64 + lane) * 8;
    *(bf16x8*)&vfh[base] = H;
    *(bf16x8*)&vfl[base] = L;
}

// ---------------------------------------------------------------------------
// prep 4: bias4 + zero page
// ---------------------------------------------------------------------------
__global__ void prep_bias(const float* __restrict__ b_ih, const float* __restrict__ b_hh,
                          float* __restrict__ bias4, float* __restrict__ zerob) {
    int c = threadIdx.x;                             // 128 threads
    float4 v = make_float4(b_ih[c] + b_hh[c],
                           b_ih[CDIM + c] + b_hh[CDIM + c],
                           b_ih[256 + c],
                           b_hh[256 + c]);
    *(float4*)&bias4[c * 4] = v;
    zerob[c] = 0.f;
}

// ---------------------------------------------------------------------------
// Gather kernel: agg[r] = sum_k xsrc[e[r,k]] for 8 rows/block.
// 64 global_load_lds (1KB each, per-lane addresses, padding -> zero page)
// keep 64KB in flight per block; then LDS 16-row sum; store packed hi/lo bf16.
// ---------------------------------------------------------------------------
__global__ __launch_bounds__(256) void gather_kernel(
        const float* __restrict__ xsrc, const int* __restrict__ eidx,
        const float* __restrict__ zerob, unsigned int* __restrict__ aggp, int N) {
    __shared__ float stage[GROWS * 16][CDIM];        // 64 KB
    const int tid  = threadIdx.x;
    const int wave = tid >> 6, lane = tid & 63;
    int brow = blockIdx.x * GROWS;
    if (brow + GROWS > N) brow = N - GROWS;

    // wave-uniform: 8 int4 covering neighbor-flat indices nr = 32w .. 32w+31
    const int4* ebase = (const int4*)&eidx[(size_t)brow * 16 + wave * 32];
    int4 ev[8];
    #pragma unroll
    for (int t = 0; t < 8; ++t) ev[t] = ebase[t];

    const int hi   = lane >> 5;                      // which row of the pair
    const int coff = (lane & 31) << 2;               // float offset within row

    #pragma unroll
    for (int t = 0; t < 8; ++t) {
        int eiA = hi ? ev[t].y : ev[t].x;            // instr j=2t: rows 4t, 4t+1
        const float* sA = (eiA < N) ? (xsrc + (size_t)eiA * CDIM) : zerob;
        load_lds16(sA + coff, &stage[wave * 32 + 4 * t][0]);
        int eiB = hi ? ev[t].w : ev[t].z;            // instr j=2t+1: rows 4t+2, 4t+3
        const float* sB = (eiB < N) ? (xsrc + (size_t)eiB * CDIM) : zerob;
        load_lds16(sB + coff, &stage[wave * 32 + 4 * t + 2][0]);
    }
    __syncthreads();                                 // drains vmcnt

    // sum 16 neighbor rows -> agg row; thread = (r = tid>>5, c4)
    const int r  = tid >> 5;
    const int c4 = (tid & 31) << 2;
    float4 a = make_float4(0.f, 0.f, 0.f, 0.f);
    #pragma unroll
    for (int k = 0; k < 16; ++k) {
        float4 v = *(const float4*)&stage[r * 16 + k][c4];
        a.x += v.x; a.y += v.y; a.z += v.z; a.w += v.w;
    }
    uint4 p;
    p.x = packf(a.x); p.y = packf(a.y); p.z = packf(a.z); p.w = packf(a.w);
    *(uint4*)&aggp[(size_t)(brow + r) * CDIM + c4] = p;
}

// ---------------------------------------------------------------------------
// GRU kernel: U=[agg|h] bf16 hi/lo in LDS -> MFMA G = U @ V -> in-register
// GRU elementwise (no gate exchange) -> hout.
// 32 rows/block, 4 waves. Wave w owns col-tiles ct = g*8 + 2w + {0,1} for all
// 4 gates g -> each lane holds all 4 gate values of its output elements.
// aggp may alias hout (row-exclusive, read-before-write within block).
// ---------------------------------------------------------------------------
__global__ __launch_bounds__(256, 4) void gru_kernel(
        const float* __restrict__ hin, const unsigned int* __restrict__ aggp,
        const __bf16* __restrict__ vfh, const __bf16* __restrict__ vfl,
        const float* __restrict__ bias4, float* __restrict__ hout, int N) {
    __shared__ char smem[32768];                     // U hi (16K) + U lo (16K)
    const int tid  = threadIdx.x;
    const int brow = blockIdx.x * BROWS;

    // ---- stage U rows (swizzled LDS) ----
    #pragma unroll 2
    for (int i = 0; i < 4; ++i) {
        int t = tid + i * 256;
        int r = t >> 5, c4 = (t & 31) << 2;
        int gr = brow + r;
        uint4  p  = make_uint4(0u, 0u, 0u, 0u);
        float4 hv = make_float4(0.f, 0.f, 0.f, 0.f);
        if (gr < N) {
            p  = *(const uint4*)&aggp[(size_t)gr * CDIM + c4];
            hv = *(const float4*)&hin[(size_t)gr * CDIM + c4];
        }
        // agg part at k=c4 (already split hi/lo)
        {
            uint off = (uint)((r * 256 + c4) * 2) ^ (uint)((r & 7) << 4);
            u16x4 h4 = {(unsigned short)(p.x >> 16), (unsigned short)(p.y >> 16),
                        (unsigned short)(p.z >> 16), (unsigned short)(p.w >> 16)};
            u16x4 l4 = {(unsigned short)(p.x & 0xffff), (unsigned short)(p.y & 0xffff),
                        (unsigned short)(p.z & 0xffff), (unsigned short)(p.w & 0xffff)};
            *(u16x4*)(smem + off)         = h4;
            *(u16x4*)(smem + 16384 + off) = l4;
        }
        // h part at k=128+c4
        {
            uint off = (uint)((r * 256 + 128 + c4) * 2) ^ (uint)((r & 7) << 4);
            unsigned int q0 = packf(hv.x), q1 = packf(hv.y), q2 = packf(hv.z), q3 = packf(hv.w);
            u16x4 h4 = {(unsigned short)(q0 >> 16), (unsigned short)(q1 >> 16),
                        (unsigned short)(q2 >> 16), (unsigned short)(q3 >> 16)};
            u16x4 l4 = {(unsigned short)(q0 & 0xffff), (unsigned short)(q1 & 0xffff),
                        (unsigned short)(q2 & 0xffff), (unsigned short)(q3 & 0xffff)};
            *(u16x4*)(smem + off)         = h4;
            *(u16x4*)(smem + 16384 + off) = l4;
        }
    }
    __syncthreads();

    // ---- MFMA phase ----
    const int wave = tid >> 6, lane = tid & 63;
    const int lrow = lane & 15, lk = (lane >> 4) * 8;
    f32x4 acc[4][2][2];                              // [gate][j][rt]
    #pragma unroll
    for (int g = 0; g < 4; ++g)
        #pragma unroll
        for (int j = 0; j < 2; ++j)
            #pragma unroll
            for (int rt = 0; rt < 2; ++rt) acc[g][j][rt] = (f32x4){0.f, 0.f, 0.f, 0.f};

    #pragma unroll 1
    for (int kt = 0; kt < 8; ++kt) {
        bf16x8 ah[2], al[2];
        #pragma unroll
        for (int rt = 0; rt < 2; ++rt) {
            int row = rt * 16 + lrow;
            uint off = (uint)((row * 256 + kt * 32 + lk) * 2) ^ (uint)((row & 7) << 4);
            ah[rt] = *(const bf16x8*)(smem + off);
            al[rt] = *(const bf16x8*)(smem + 16384 + off);
        }
        #pragma unroll
        for (int g = 0; g < 4; ++g) {
            if (g == 2 && kt >= 4) continue;         // i_n: only agg K-half
            if (g == 3 && kt < 4)  continue;         // h_n: only h K-half
            #pragma unroll
            for (int j = 0; j < 2; ++j) {
                int ct = g * 8 + 2 * wave + j;
                const __bf16* bp = vfh + ((size_t)(kt * 32 + ct) * 64 + lane) * 8;
                const __bf16* lp = vfl + ((size_t)(kt * 32 + ct) * 64 + lane) * 8;
                bf16x8 bh = *(const bf16x8*)bp;
                bf16x8 bl = *(const bf16x8*)lp;
                #pragma unroll
                for (int rt = 0; rt < 2; ++rt) {
                    acc[g][j][rt] = mfma16(ah[rt], bh, acc[g][j][rt]);
                    acc[g][j][rt] = mfma16(al[rt], bh, acc[g][j][rt]);
                    acc[g][j][rt] = mfma16(ah[rt], bl, acc[g][j][rt]);
                }
            }
        }
    }

    // ---- in-register epilogue ----
    const int q = lane >> 4;
    #pragma unroll
    for (int j = 0; j < 2; ++j) {
        int c = 32 * wave + j * 16 + lrow;
        float4 b = *(const float4*)&bias4[c * 4];
        #pragma unroll
        for (int rt = 0; rt < 2; ++rt) {
            #pragma unroll
            for (int reg = 0; reg < 4; ++reg) {
                int n  = rt * 16 + q * 4 + reg;
                int gr = brow + n;
                float rv = acc[0][j][rt][reg] + b.x;
                float zv = acc[1][j][rt][reg] + b.y;
                float nv = acc[2][j][rt][reg] + b.z;
                float hv = acc[3][j][rt][reg] + b.w;
                float rr = 1.f / (1.f + __expf(-rv));
                float zz = 1.f / (1.f + __expf(-zv));
                float nn = tanhf(nv + rr * hv);
                if (gr < N) {
                    float h = hin[(size_t)gr * CDIM + c];
                    hout[(size_t)gr * CDIM + c] = (1.f - zz) * nn + zz * h;
                }
            }
        }
    }
}

// ---------------------------------------------------------------------------
extern "C" void kernel_launch(void* const* d_in, const int* in_sizes, int n_in,
                              void* d_out, int out_size, void* d_ws, size_t ws_size,
                              hipStream_t stream) {
    const float* x      = (const float*)d_in[0];
    const int*   eidx   = (const int*)  d_in[1];
    const float* weight = (const float*)d_in[2];
    const float* w_ih   = (const float*)d_in[3];
    const float* w_hh   = (const float*)d_in[4];
    const float* b_ih   = (const float*)d_in[5];
    const float* b_hh   = (const float*)d_in[6];
    float* out = (float*)d_out;

    const int N = in_sizes[0] / CDIM;

    char* p = (char*)d_ws;
    float*  bufA  = (float*)p;  p += (size_t)N * CDIM * 4;
    float*  Wc    = (float*)p;  p += (size_t)NLAYER * CDIM * C3 * 4;
    float*  wT    = (float*)p;  p += (size_t)CDIM * C3 * 4;
    float*  bias4 = (float*)p;  p += 512 * 4;
    float*  zerob = (float*)p;  p += CDIM * 4;
    __bf16* vfh   = (__bf16*)p; p += (size_t)NLAYER * 131072 * 2;
    __bf16* vfl   = (__bf16*)p;

    prep_transpose<<<192, 256, 0, stream>>>(w_ih, wT);
    prep_wc<<<NLAYER * CDIM, 256, 0, stream>>>(weight, wT, Wc);
    prep_pack<<<192, 256, 0, stream>>>(Wc, w_hh, vfh, vfl);
    prep_bias<<<1, 128, 0, stream>>>(b_ih, b_hh, bias4, zerob);

    const int nbG = (N + GROWS - 1) / GROWS;
    const int nbB = (N + BROWS - 1) / BROWS;
    const size_t VSZ = 131072;

    // layer 1: agg aliases out
    gather_kernel<<<nbG, 256, 0, stream>>>(x, eidx, zerob, (unsigned int*)out, N);
    gru_kernel<<<nbB, 256, 0, stream>>>(x, (const unsigned int*)out, vfh, vfl, bias4, out, N);
    // layer 2: agg aliases bufA
    gather_kernel<<<nbG, 256, 0, stream>>>(out, eidx, zerob, (unsigned int*)bufA, N);
    gru_kernel<<<nbB, 256, 0, stream>>>(out, (const unsigned int*)bufA, vfh + VSZ, vfl + VSZ, bias4, bufA, N);
    // layer 3: agg aliases out
    gather_kernel<<<nbG, 256, 0, stream>>>(bufA, eidx, zerob, (unsigned int*)out, N);
    gru_kernel<<<nbB, 256, 0, stream>>>(bufA, (const unsigned int*)out, vfh + 2 * VSZ, vfl + 2 * VSZ, bias4, out, N);
}

// Round 5
// 868.358 us; speedup vs baseline: 1.0288x; 1.0288x over previous
//
#include <hip/hip_runtime.h>

#define CDIM 128
#define C3   384
#define NLAYER 3
#define BROWS 32     // rows per GRU block
#define GROWS 8      // rows per gather block
#define SL    4      // pipeline slices per layer

typedef __attribute__((ext_vector_type(8))) __bf16 bf16x8;
typedef __attribute__((ext_vector_type(4))) float  f32x4;
typedef __attribute__((ext_vector_type(4))) unsigned short u16x4;

static __device__ __forceinline__ f32x4 mfma16(bf16x8 a, bf16x8 b, f32x4 c) {
    return __builtin_amdgcn_mfma_f32_16x16x32_bf16(a, b, c, 0, 0, 0);
}

// async global->LDS, 16B per lane; LDS dest = uniform base + lane*16
static __device__ __forceinline__ void load_lds16(const float* g, float* l) {
    __builtin_amdgcn_global_load_lds(
        (const __attribute__((address_space(1))) unsigned int*)(const void*)g,
        (__attribute__((address_space(3))) unsigned int*)(void*)l,
        16, 0, 0);
}

// f32 -> packed (bf16_hi << 16) | bf16_lo  with lo = v - hi
static __device__ __forceinline__ unsigned int packf(float v) {
    __bf16 h = (__bf16)v;
    __bf16 l = (__bf16)(v - (float)h);
    unsigned short hb, lb;
    __builtin_memcpy(&hb, &h, 2);
    __builtin_memcpy(&lb, &l, 2);
    return ((unsigned int)hb << 16) | lb;
}

// ---------------------------------------------------------------------------
// prep 1: wT[j][c] = w_ih[c][j]
// ---------------------------------------------------------------------------
__global__ __launch_bounds__(256) void prep_transpose(const float* __restrict__ w_ih,
                                                      float* __restrict__ wT) {
    int idx = blockIdx.x * 256 + threadIdx.x;       // 128*384
    int j = idx / C3, c = idx % C3;
    wT[idx] = w_ih[c * CDIM + j];
}

// ---------------------------------------------------------------------------
// prep 2: Wc[l][p][c] = sum_j W[l][p][j] * w_ih[c][j]
// ---------------------------------------------------------------------------
__global__ __launch_bounds__(256) void prep_wc(const float* __restrict__ weight,
                                               const float* __restrict__ wT,
                                               float* __restrict__ Wc) {
    __shared__ float wrow[CDIM];
    const int b = blockIdx.x;                        // l*128 + p
    if (threadIdx.x < CDIM) wrow[threadIdx.x] = weight[(size_t)b * CDIM + threadIdx.x];
    __syncthreads();
    for (int c = threadIdx.x; c < C3; c += 256) {
        float acc = 0.f;
        #pragma unroll 8
        for (int j = 0; j < CDIM; ++j) acc = fmaf(wrow[j], wT[j * C3 + c], acc);
        Wc[(size_t)b * C3 + c] = acc;
    }
}

// ---------------------------------------------------------------------------
// prep 3: pack V[256][512] (= [s_r | s_z | i_n | h_n]) into MFMA fragment
// order, bf16 hi/lo.  frag(kt,ct): lane l, j -> V[kt*32+(l>>4)*8+j][ct*16+(l&15)]
// ---------------------------------------------------------------------------
__global__ __launch_bounds__(256) void prep_pack(const float* __restrict__ Wc,
                                                 const float* __restrict__ w_hh,
                                                 __bf16* __restrict__ vfh,
                                                 __bf16* __restrict__ vfl) {
    const int fid  = blockIdx.x * 4 + (threadIdx.x >> 6);   // 0..767 = l*256 + kt*32 + ct
    const int lane = threadIdx.x & 63;
    const int l    = fid >> 8;
    const int rem  = fid & 255;
    const int kt   = rem >> 5, ct = rem & 31;
    const int kbase = kt * 32 + (lane >> 4) * 8;
    const int c     = ct * 16 + (lane & 15);

    bf16x8 H, L;
    #pragma unroll
    for (int j = 0; j < 8; ++j) {
        int k = kbase + j;
        float v;
        if (k < CDIM) {
            v = (c < C3) ? Wc[((size_t)l * CDIM + k) * C3 + c] : 0.f;
        } else {
            int q = k - CDIM;
            if (c < 256)      v = w_hh[(size_t)c * CDIM + q];          // r,z rows
            else if (c < C3)  v = 0.f;                                  // i_n: no h part
            else              v = w_hh[(size_t)(c - CDIM) * CDIM + q];  // n rows 256..383
        }
        __bf16 h = (__bf16)v;
        H[j] = h;
        L[j] = (__bf16)(v - (float)h);
    }
    size_t base = ((size_t)fid * 64 + lane) * 8;
    *(bf16x8*)&vfh[base] = H;
    *(bf16x8*)&vfl[base] = L;
}

// ---------------------------------------------------------------------------
// prep 4: bias4 + zero page
// ---------------------------------------------------------------------------
__global__ void prep_bias(const float* __restrict__ b_ih, const float* __restrict__ b_hh,
                          float* __restrict__ bias4, float* __restrict__ zerob) {
    int c = threadIdx.x;                             // 128 threads
    float4 v = make_float4(b_ih[c] + b_hh[c],
                           b_ih[CDIM + c] + b_hh[CDIM + c],
                           b_ih[256 + c],
                           b_hh[256 + c]);
    *(float4*)&bias4[c * 4] = v;
    zerob[c] = 0.f;
}

// ---------------------------------------------------------------------------
// Pipelined kernel: blocks [0, nG) gather slice [gB,gE); blocks [nG, nG+nU)
// run the GRU for slice [uB,uE) (filled by the PREVIOUS dispatch's gather).
// Roles touch disjoint rows of aggp/hout -> race-free within a dispatch.
// ---------------------------------------------------------------------------
__global__ __launch_bounds__(256) void pipe_kernel(
        const float* __restrict__ hin, const int* __restrict__ eidx,
        const float* __restrict__ zerob, unsigned int* __restrict__ aggp,
        const __bf16* __restrict__ vfh, const __bf16* __restrict__ vfl,
        const float* __restrict__ bias4, float* __restrict__ hout,
        int N, int nG, int gB, int gE, int uB, int uE) {
    __shared__ char smem[65536];
    const int tid  = threadIdx.x;
    const int wave = tid >> 6, lane = tid & 63;

    if ((int)blockIdx.x < nG) {
        // ================= GATHER role =================
        float (*stage)[CDIM] = (float(*)[CDIM])smem;     // [128][128] f32
        int brow = gB + (int)blockIdx.x * GROWS;
        if (brow + GROWS > gE) brow = gE - GROWS;        // duplicate rows: benign

        const int4* ebase = (const int4*)&eidx[(size_t)brow * 16 + wave * 32];
        int4 ev[8];
        #pragma unroll
        for (int t = 0; t < 8; ++t) ev[t] = ebase[t];

        const int hi   = lane >> 5;
        const int coff = (lane & 31) << 2;

        #pragma unroll
        for (int t = 0; t < 8; ++t) {
            int eiA = hi ? ev[t].y : ev[t].x;            // rows 4t, 4t+1
            const float* sA = (eiA < N) ? (hin + (size_t)eiA * CDIM) : zerob;
            load_lds16(sA + coff, &stage[wave * 32 + 4 * t][0]);
            int eiB = hi ? ev[t].w : ev[t].z;            // rows 4t+2, 4t+3
            const float* sB = (eiB < N) ? (hin + (size_t)eiB * CDIM) : zerob;
            load_lds16(sB + coff, &stage[wave * 32 + 4 * t + 2][0]);
        }
        __syncthreads();                                 // drains vmcnt

        const int r  = tid >> 5;
        const int c4 = (tid & 31) << 2;
        float4 a = make_float4(0.f, 0.f, 0.f, 0.f);
        #pragma unroll
        for (int k = 0; k < 16; ++k) {
            float4 v = *(const float4*)&stage[r * 16 + k][c4];
            a.x += v.x; a.y += v.y; a.z += v.z; a.w += v.w;
        }
        uint4 p;
        p.x = packf(a.x); p.y = packf(a.y); p.z = packf(a.z); p.w = packf(a.w);
        *(uint4*)&aggp[(size_t)(brow + r) * CDIM + c4] = p;
        return;
    }

    // ================= GRU role =================
    const int brow = uB + ((int)blockIdx.x - nG) * BROWS;

    // ---- stage U rows (swizzled LDS, hi at 0, lo at 16K) ----
    #pragma unroll
    for (int i = 0; i < 4; ++i) {
        int t = tid + i * 256;
        int r = t >> 5, c4 = (t & 31) << 2;
        int gr = brow + r;
        uint4  p  = make_uint4(0u, 0u, 0u, 0u);
        float4 hv = make_float4(0.f, 0.f, 0.f, 0.f);
        if (gr < uE) {
            p  = *(const uint4*)&aggp[(size_t)gr * CDIM + c4];
            hv = *(const float4*)&hin[(size_t)gr * CDIM + c4];
        }
        {
            uint off = (uint)((r * 256 + c4) * 2) ^ (uint)((r & 7) << 4);
            u16x4 h4 = {(unsigned short)(p.x >> 16), (unsigned short)(p.y >> 16),
                        (unsigned short)(p.z >> 16), (unsigned short)(p.w >> 16)};
            u16x4 l4 = {(unsigned short)(p.x & 0xffff), (unsigned short)(p.y & 0xffff),
                        (unsigned short)(p.z & 0xffff), (unsigned short)(p.w & 0xffff)};
            *(u16x4*)(smem + off)         = h4;
            *(u16x4*)(smem + 16384 + off) = l4;
        }
        {
            uint off = (uint)((r * 256 + 128 + c4) * 2) ^ (uint)((r & 7) << 4);
            unsigned int q0 = packf(hv.x), q1 = packf(hv.y), q2 = packf(hv.z), q3 = packf(hv.w);
            u16x4 h4 = {(unsigned short)(q0 >> 16), (unsigned short)(q1 >> 16),
                        (unsigned short)(q2 >> 16), (unsigned short)(q3 >> 16)};
            u16x4 l4 = {(unsigned short)(q0 & 0xffff), (unsigned short)(q1 & 0xffff),
                        (unsigned short)(q2 & 0xffff), (unsigned short)(q3 & 0xffff)};
            *(u16x4*)(smem + off)         = h4;
            *(u16x4*)(smem + 16384 + off) = l4;
        }
    }
    __syncthreads();

    // ---- MFMA phase ----
    const int lrow = lane & 15, lk = (lane >> 4) * 8;
    f32x4 acc[4][2][2];                              // [gate][j][rt]
    #pragma unroll
    for (int g = 0; g < 4; ++g)
        #pragma unroll
        for (int j = 0; j < 2; ++j)
            #pragma unroll
            for (int rt = 0; rt < 2; ++rt) acc[g][j][rt] = (f32x4){0.f, 0.f, 0.f, 0.f};

    #pragma unroll 1
    for (int kt = 0; kt < 8; ++kt) {
        bf16x8 ah[2], al[2];
        #pragma unroll
        for (int rt = 0; rt < 2; ++rt) {
            int row = rt * 16 + lrow;
            uint off = (uint)((row * 256 + kt * 32 + lk) * 2) ^ (uint)((row & 7) << 4);
            ah[rt] = *(const bf16x8*)(smem + off);
            al[rt] = *(const bf16x8*)(smem + 16384 + off);
        }
        #pragma unroll
        for (int g = 0; g < 4; ++g) {
            if (g == 2 && kt >= 4) continue;         // i_n: only agg K-half
            if (g == 3 && kt < 4)  continue;         // h_n: only h K-half
            #pragma unroll
            for (int j = 0; j < 2; ++j) {
                int ct = g * 8 + 2 * wave + j;
                bf16x8 bh = *(const bf16x8*)(vfh + ((size_t)(kt * 32 + ct) * 64 + lane) * 8);
                bf16x8 bl = *(const bf16x8*)(vfl + ((size_t)(kt * 32 + ct) * 64 + lane) * 8);
                #pragma unroll
                for (int rt = 0; rt < 2; ++rt) {
                    acc[g][j][rt] = mfma16(ah[rt], bh, acc[g][j][rt]);
                    acc[g][j][rt] = mfma16(al[rt], bh, acc[g][j][rt]);
                    acc[g][j][rt] = mfma16(ah[rt], bl, acc[g][j][rt]);
                }
            }
        }
    }

    // ---- in-register epilogue ----
    const int q = lane >> 4;
    #pragma unroll
    for (int j = 0; j < 2; ++j) {
        int c = 32 * wave + j * 16 + lrow;
        float4 b = *(const float4*)&bias4[c * 4];
        #pragma unroll
        for (int rt = 0; rt < 2; ++rt) {
            #pragma unroll
            for (int reg = 0; reg < 4; ++reg) {
                int n  = rt * 16 + q * 4 + reg;
                int gr = brow + n;
                float rv = acc[0][j][rt][reg] + b.x;
                float zv = acc[1][j][rt][reg] + b.y;
                float nv = acc[2][j][rt][reg] + b.z;
                float hv = acc[3][j][rt][reg] + b.w;
                float rr = 1.f / (1.f + __expf(-rv));
                float zz = 1.f / (1.f + __expf(-zv));
                float nn = tanhf(nv + rr * hv);
                if (gr < uE) {
                    float h = hin[(size_t)gr * CDIM + c];
                    hout[(size_t)gr * CDIM + c] = (1.f - zz) * nn + zz * h;
                }
            }
        }
    }
}

// ---------------------------------------------------------------------------
extern "C" void kernel_launch(void* const* d_in, const int* in_sizes, int n_in,
                              void* d_out, int out_size, void* d_ws, size_t ws_size,
                              hipStream_t stream) {
    const float* x      = (const float*)d_in[0];
    const int*   eidx   = (const int*)  d_in[1];
    const float* weight = (const float*)d_in[2];
    const float* w_ih   = (const float*)d_in[3];
    const float* w_hh   = (const float*)d_in[4];
    const float* b_ih   = (const float*)d_in[5];
    const float* b_hh   = (const float*)d_in[6];
    float* out = (float*)d_out;

    const int N = in_sizes[0] / CDIM;

    char* p = (char*)d_ws;
    float*  bufA  = (float*)p;  p += (size_t)N * CDIM * 4;
    float*  Wc    = (float*)p;  p += (size_t)NLAYER * CDIM * C3 * 4;
    float*  wT    = (float*)p;  p += (size_t)CDIM * C3 * 4;
    float*  bias4 = (float*)p;  p += 512 * 4;
    float*  zerob = (float*)p;  p += CDIM * 4;
    __bf16* vfh   = (__bf16*)p; p += (size_t)NLAYER * 131072 * 2;
    __bf16* vfl   = (__bf16*)p;

    prep_transpose<<<192, 256, 0, stream>>>(w_ih, wT);
    prep_wc<<<NLAYER * CDIM, 256, 0, stream>>>(weight, wT, Wc);
    prep_pack<<<192, 256, 0, stream>>>(Wc, w_hh, vfh, vfl);
    prep_bias<<<1, 128, 0, stream>>>(b_ih, b_hh, bias4, zerob);

    const size_t VSZ = 131072;
    const int SR = (((N + SL - 1) / SL) + 31) / 32 * 32;   // slice rows

    auto run_layer = [&](const float* hin, unsigned int* aggp, float* hout,
                         const __bf16* vh, const __bf16* vl) {
        for (int j = 0; j <= SL; ++j) {
            int gB = 0, gE = 0, nG = 0, uB = 0, uE = 0, nU = 0;
            if (j < SL) {
                gB = j * SR; gE = (gB + SR < N) ? gB + SR : N;
                if (gE > gB) nG = (gE - gB + GROWS - 1) / GROWS;
            }
            if (j > 0) {
                uB = (j - 1) * SR; uE = (uB + SR < N) ? uB + SR : N;
                if (uE > uB) nU = (uE - uB + BROWS - 1) / BROWS;
            }
            if (nG + nU == 0) continue;
            pipe_kernel<<<nG + nU, 256, 0, stream>>>(hin, eidx, zerob, aggp,
                                                     vh, vl, bias4, hout,
                                                     N, nG, gB, gE, uB, uE);
        }
    };

    run_layer(x,    (unsigned int*)out,  out,  vfh,           vfl);
    run_layer(out,  (unsigned int*)bufA, bufA, vfh + VSZ,     vfl + VSZ);
    run_layer(bufA, (unsigned int*)out,  out,  vfh + 2 * VSZ, vfl + 2 * VSZ);
}

// Round 6
// 849.745 us; speedup vs baseline: 1.0514x; 1.0219x over previous
//
#include <hip/hip_runtime.h>

#define CDIM 128
#define C3   384
#define NLAYER 3
#define BROWS 32     // rows per fused block (4 iters x 2 rows/wave x 4 waves)

typedef __attribute__((ext_vector_type(8))) __bf16 bf16x8;
typedef __attribute__((ext_vector_type(4))) float  f32x4;
typedef __attribute__((ext_vector_type(4))) unsigned short u16x4;

static __device__ __forceinline__ f32x4 mfma16(bf16x8 a, bf16x8 b, f32x4 c) {
    return __builtin_amdgcn_mfma_f32_16x16x32_bf16(a, b, c, 0, 0, 0);
}

// async global->LDS, 16B per lane; LDS dest = uniform base + lane*16
static __device__ __forceinline__ void load_lds16(const float* g, float* l) {
    __builtin_amdgcn_global_load_lds(
        (const __attribute__((address_space(1))) unsigned int*)(const void*)g,
        (__attribute__((address_space(3))) unsigned int*)(void*)l,
        16, 0, 0);
}

// f32 -> packed (bf16_hi << 16) | bf16_lo  with lo = v - hi
static __device__ __forceinline__ unsigned int packf(float v) {
    __bf16 h = (__bf16)v;
    __bf16 l = (__bf16)(v - (float)h);
    unsigned short hb, lb;
    __builtin_memcpy(&hb, &h, 2);
    __builtin_memcpy(&lb, &l, 2);
    return ((unsigned int)hb << 16) | lb;
}

// ---------------------------------------------------------------------------
// prep 1: wT[j][c] = w_ih[c][j]
// ---------------------------------------------------------------------------
__global__ __launch_bounds__(256) void prep_transpose(const float* __restrict__ w_ih,
                                                      float* __restrict__ wT) {
    int idx = blockIdx.x * 256 + threadIdx.x;       // 128*384
    int j = idx / C3, c = idx % C3;
    wT[idx] = w_ih[c * CDIM + j];
}

// ---------------------------------------------------------------------------
// prep 2: Wc[l][p][c] = sum_j W[l][p][j] * w_ih[c][j]
// ---------------------------------------------------------------------------
__global__ __launch_bounds__(256) void prep_wc(const float* __restrict__ weight,
                                               const float* __restrict__ wT,
                                               float* __restrict__ Wc) {
    __shared__ float wrow[CDIM];
    const int b = blockIdx.x;                        // l*128 + p
    if (threadIdx.x < CDIM) wrow[threadIdx.x] = weight[(size_t)b * CDIM + threadIdx.x];
    __syncthreads();
    for (int c = threadIdx.x; c < C3; c += 256) {
        float acc = 0.f;
        #pragma unroll 8
        for (int j = 0; j < CDIM; ++j) acc = fmaf(wrow[j], wT[j * C3 + c], acc);
        Wc[(size_t)b * C3 + c] = acc;
    }
}

// ---------------------------------------------------------------------------
// prep 3: pack V[256][512] (= [s_r | s_z | i_n | h_n]) into MFMA fragment
// order, bf16 hi/lo.  frag(kt,ct): lane l, j -> V[kt*32+(l>>4)*8+j][ct*16+(l&15)]
// ---------------------------------------------------------------------------
__global__ __launch_bounds__(256) void prep_pack(const float* __restrict__ Wc,
                                                 const float* __restrict__ w_hh,
                                                 __bf16* __restrict__ vfh,
                                                 __bf16* __restrict__ vfl) {
    const int fid  = blockIdx.x * 4 + (threadIdx.x >> 6);   // 0..767 = l*256 + kt*32 + ct
    const int lane = threadIdx.x & 63;
    const int l    = fid >> 8;
    const int rem  = fid & 255;
    const int kt   = rem >> 5, ct = rem & 31;
    const int kbase = kt * 32 + (lane >> 4) * 8;
    const int c     = ct * 16 + (lane & 15);

    bf16x8 H, L;
    #pragma unroll
    for (int j = 0; j < 8; ++j) {
        int k = kbase + j;
        float v;
        if (k < CDIM) {
            v = (c < C3) ? Wc[((size_t)l * CDIM + k) * C3 + c] : 0.f;
        } else {
            int q = k - CDIM;
            if (c < 256)      v = w_hh[(size_t)c * CDIM + q];          // r,z rows
            else if (c < C3)  v = 0.f;                                  // i_n: no h part
            else              v = w_hh[(size_t)(c - CDIM) * CDIM + q];  // n rows 256..383
        }
        __bf16 h = (__bf16)v;
        H[j] = h;
        L[j] = (__bf16)(v - (float)h);
    }
    size_t base = ((size_t)fid * 64 + lane) * 8;
    *(bf16x8*)&vfh[base] = H;
    *(bf16x8*)&vfl[base] = L;
}

// ---------------------------------------------------------------------------
// prep 4: bias4 + zero page
// ---------------------------------------------------------------------------
__global__ void prep_bias(const float* __restrict__ b_ih, const float* __restrict__ b_hh,
                          float* __restrict__ bias4, float* __restrict__ zerob) {
    int c = threadIdx.x;                             // 128 threads
    float4 v = make_float4(b_ih[c] + b_hh[c],
                           b_ih[CDIM + c] + b_hh[CDIM + c],
                           b_ih[256 + c],
                           b_hh[256 + c]);
    *(float4*)&bias4[c * 4] = v;
    zerob[c] = 0.f;
}

// ---------------------------------------------------------------------------
// Fused layer: per block, 32 rows. 4 wave-private iterations:
//   DMA 2 rows x 16 neighbors (16KB) into wave-private stage, per-wave
//   vmcnt(0) wait (no barrier), f32 sum into registers, h row prefetch.
// Then: barrier -> reuse stage LDS as swizzled U=[agg|h] hi/lo tile ->
// barrier -> MFMA G = U @ V (wave w owns col pair per gate, gates land in
// the same lane) -> in-register GRU epilogue (h from LDS hi+lo) -> hout.
// agg never touches global memory.
// ---------------------------------------------------------------------------
__global__ __launch_bounds__(256, 2) void fused_layer(
        const float* __restrict__ hin, const int* __restrict__ eidx,
        const float* __restrict__ zerob,
        const __bf16* __restrict__ vfh, const __bf16* __restrict__ vfl,
        const float* __restrict__ bias4, float* __restrict__ hout, int N) {
    __shared__ char smem[65536];
    const int tid  = threadIdx.x;
    const int wave = tid >> 6, lane = tid & 63;
    const int brow = blockIdx.x * BROWS;

    float* stage_w = (float*)(smem + wave * 16384);  // 32 rows x 512B, wave-private
    const int hi   = lane >> 5;                      // row of the pair
    const int coff = (lane & 31) << 2;               // float col offset

    float4 areg[4], hreg[4];

    // ---- gather phase: 4 iterations, no barriers ----
    #pragma unroll 1
    for (int i = 0; i < 4; ++i) {
        const int r0 = brow + i * 8 + wave * 2;      // rows r0, r0+1
        const int rA = (r0     < N) ? r0     : N - 1;
        const int rB = (r0 + 1 < N) ? r0 + 1 : N - 1;
        int4 ev[8];
        {
            const int4* eA = (const int4*)&eidx[(size_t)rA * 16];
            const int4* eB = (const int4*)&eidx[(size_t)rB * 16];
            #pragma unroll
            for (int t = 0; t < 4; ++t) { ev[t] = eA[t]; ev[t + 4] = eB[t]; }
        }
        #pragma unroll
        for (int t = 0; t < 8; ++t) {
            int eiA = hi ? ev[t].y : ev[t].x;        // stage rows 4t, 4t+1
            const float* sA = (eiA < N) ? (hin + (size_t)eiA * CDIM) : zerob;
            load_lds16(sA + coff, stage_w + (4 * t) * CDIM);
            int eiB = hi ? ev[t].w : ev[t].z;        // stage rows 4t+2, 4t+3
            const float* sB = (eiB < N) ? (hin + (size_t)eiB * CDIM) : zerob;
            load_lds16(sB + coff, stage_w + (4 * t + 2) * CDIM);
        }
        // h row prefetch (same vmcnt window)
        {
            int hr = r0 + hi;
            float4 hv = make_float4(0.f, 0.f, 0.f, 0.f);
            if (hr < N) hv = *(const float4*)&hin[(size_t)hr * CDIM + coff];
            hreg[i] = hv;
        }
        asm volatile("s_waitcnt vmcnt(0)" ::: "memory");
        __builtin_amdgcn_sched_barrier(0);

        // sum 16 neighbor rows (wave-private stage; lane = (hi, coff))
        float4 a = make_float4(0.f, 0.f, 0.f, 0.f);
        #pragma unroll
        for (int j = 0; j < 16; ++j) {
            float4 v = *(const float4*)(stage_w + (hi * 16 + j) * CDIM + coff);
            a.x += v.x; a.y += v.y; a.z += v.z; a.w += v.w;
        }
        areg[i] = a;
    }
    __syncthreads();                                 // all stage reads done

    // ---- build swizzled U tile in reused LDS (hi plane @0, lo plane @16K) ----
    #pragma unroll
    for (int i = 0; i < 4; ++i) {
        int r = i * 8 + wave * 2 + hi;               // local row 0..31
        {   // agg at cols coff..coff+3
            uint off = (uint)((r * 256 + coff) * 2) ^ (uint)((r & 7) << 4);
            uint p0 = packf(areg[i].x), p1 = packf(areg[i].y),
                 p2 = packf(areg[i].z), p3 = packf(areg[i].w);
            u16x4 h4 = {(unsigned short)(p0 >> 16), (unsigned short)(p1 >> 16),
                        (unsigned short)(p2 >> 16), (unsigned short)(p3 >> 16)};
            u16x4 l4 = {(unsigned short)(p0 & 0xffff), (unsigned short)(p1 & 0xffff),
                        (unsigned short)(p2 & 0xffff), (unsigned short)(p3 & 0xffff)};
            *(u16x4*)(smem + off)         = h4;
            *(u16x4*)(smem + 16384 + off) = l4;
        }
        {   // h at cols 128+coff
            uint off = (uint)((r * 256 + 128 + coff) * 2) ^ (uint)((r & 7) << 4);
            uint p0 = packf(hreg[i].x), p1 = packf(hreg[i].y),
                 p2 = packf(hreg[i].z), p3 = packf(hreg[i].w);
            u16x4 h4 = {(unsigned short)(p0 >> 16), (unsigned short)(p1 >> 16),
                        (unsigned short)(p2 >> 16), (unsigned short)(p3 >> 16)};
            u16x4 l4 = {(unsigned short)(p0 & 0xffff), (unsigned short)(p1 & 0xffff),
                        (unsigned short)(p2 & 0xffff), (unsigned short)(p3 & 0xffff)};
            *(u16x4*)(smem + off)         = h4;
            *(u16x4*)(smem + 16384 + off) = l4;
        }
    }
    __syncthreads();

    // ---- MFMA phase: wave w owns ct = g*8 + 2w + {0,1} for all 4 gates ----
    const int lrow = lane & 15, lk = (lane >> 4) * 8;
    f32x4 acc[4][2][2];                              // [gate][j][rt]
    #pragma unroll
    for (int g = 0; g < 4; ++g)
        #pragma unroll
        for (int j = 0; j < 2; ++j)
            #pragma unroll
            for (int rt = 0; rt < 2; ++rt) acc[g][j][rt] = (f32x4){0.f, 0.f, 0.f, 0.f};

    #pragma unroll 1
    for (int kt = 0; kt < 8; ++kt) {
        bf16x8 ah[2], al[2];
        #pragma unroll
        for (int rt = 0; rt < 2; ++rt) {
            int row = rt * 16 + lrow;
            uint off = (uint)((row * 256 + kt * 32 + lk) * 2) ^ (uint)((row & 7) << 4);
            ah[rt] = *(const bf16x8*)(smem + off);
            al[rt] = *(const bf16x8*)(smem + 16384 + off);
        }
        #pragma unroll
        for (int g = 0; g < 4; ++g) {
            if (g == 2 && kt >= 4) continue;         // i_n: only agg K-half
            if (g == 3 && kt < 4)  continue;         // h_n: only h K-half
            #pragma unroll
            for (int j = 0; j < 2; ++j) {
                int ct = g * 8 + 2 * wave + j;
                bf16x8 bh = *(const bf16x8*)(vfh + ((size_t)(kt * 32 + ct) * 64 + lane) * 8);
                bf16x8 bl = *(const bf16x8*)(vfl + ((size_t)(kt * 32 + ct) * 64 + lane) * 8);
                #pragma unroll
                for (int rt = 0; rt < 2; ++rt) {
                    acc[g][j][rt] = mfma16(ah[rt], bh, acc[g][j][rt]);
                    acc[g][j][rt] = mfma16(al[rt], bh, acc[g][j][rt]);
                    acc[g][j][rt] = mfma16(ah[rt], bl, acc[g][j][rt]);
                }
            }
        }
    }

    // ---- in-register epilogue (h reconstructed from LDS hi+lo) ----
    const int q = lane >> 4;
    #pragma unroll
    for (int j = 0; j < 2; ++j) {
        int c = 32 * wave + j * 16 + lrow;
        float4 b = *(const float4*)&bias4[c * 4];
        #pragma unroll
        for (int rt = 0; rt < 2; ++rt) {
            #pragma unroll
            for (int reg = 0; reg < 4; ++reg) {
                int n  = rt * 16 + q * 4 + reg;
                int gr = brow + n;
                float rv = acc[0][j][rt][reg] + b.x;
                float zv = acc[1][j][rt][reg] + b.y;
                float nv = acc[2][j][rt][reg] + b.z;
                float hv = acc[3][j][rt][reg] + b.w;
                float rr = 1.f / (1.f + __expf(-rv));
                float zz = 1.f / (1.f + __expf(-zv));
                float nn = tanhf(nv + rr * hv);
                uint off = (uint)((n * 256 + 128 + c) * 2) ^ (uint)((n & 7) << 4);
                unsigned short hb = *(const unsigned short*)(smem + off);
                unsigned short lb = *(const unsigned short*)(smem + 16384 + off);
                float h = __uint_as_float((uint)hb << 16) + __uint_as_float((uint)lb << 16);
                if (gr < N)
                    hout[(size_t)gr * CDIM + c] = (1.f - zz) * nn + zz * h;
            }
        }
    }
}

// ---------------------------------------------------------------------------
extern "C" void kernel_launch(void* const* d_in, const int* in_sizes, int n_in,
                              void* d_out, int out_size, void* d_ws, size_t ws_size,
                              hipStream_t stream) {
    const float* x      = (const float*)d_in[0];
    const int*   eidx   = (const int*)  d_in[1];
    const float* weight = (const float*)d_in[2];
    const float* w_ih   = (const float*)d_in[3];
    const float* w_hh   = (const float*)d_in[4];
    const float* b_ih   = (const float*)d_in[5];
    const float* b_hh   = (const float*)d_in[6];
    float* out = (float*)d_out;

    const int N = in_sizes[0] / CDIM;

    char* p = (char*)d_ws;
    float*  bufA  = (float*)p;  p += (size_t)N * CDIM * 4;
    float*  Wc    = (float*)p;  p += (size_t)NLAYER * CDIM * C3 * 4;
    float*  wT    = (float*)p;  p += (size_t)CDIM * C3 * 4;
    float*  bias4 = (float*)p;  p += 512 * 4;
    float*  zerob = (float*)p;  p += CDIM * 4;
    __bf16* vfh   = (__bf16*)p; p += (size_t)NLAYER * 131072 * 2;
    __bf16* vfl   = (__bf16*)p;

    prep_transpose<<<192, 256, 0, stream>>>(w_ih, wT);
    prep_wc<<<NLAYER * CDIM, 256, 0, stream>>>(weight, wT, Wc);
    prep_pack<<<192, 256, 0, stream>>>(Wc, w_hh, vfh, vfl);
    prep_bias<<<1, 128, 0, stream>>>(b_ih, b_hh, bias4, zerob);

    const int nb = (N + BROWS - 1) / BROWS;
    const size_t VSZ = 131072;
    fused_layer<<<nb, 256, 0, stream>>>(x,    eidx, zerob, vfh,           vfl,           bias4, out,  N);
    fused_layer<<<nb, 256, 0, stream>>>(out,  eidx, zerob, vfh + VSZ,     vfl + VSZ,     bias4, bufA, N);
    fused_layer<<<nb, 256, 0, stream>>>(bufA, eidx, zerob, vfh + 2 * VSZ, vfl + 2 * VSZ, bias4, out,  N);
}

// Round 8
// 825.237 us; speedup vs baseline: 1.0826x; 1.0297x over previous
//
#include <hip/hip_runtime.h>

#define CDIM 128
#define C3   384
#define NLAYER 3
#define BROWS 32     // rows per fused block (8 rows per wave)

typedef __attribute__((ext_vector_type(8))) __bf16 bf16x8;
typedef __attribute__((ext_vector_type(4))) float  f32x4;
typedef __attribute__((ext_vector_type(4))) unsigned short u16x4;

static __device__ __forceinline__ f32x4 mfma16(bf16x8 a, bf16x8 b, f32x4 c) {
    return __builtin_amdgcn_mfma_f32_16x16x32_bf16(a, b, c, 0, 0, 0);
}

// async global->LDS, 16B per lane; LDS dest = uniform base + lane*16
static __device__ __forceinline__ void load_lds16(const float* g, float* l) {
    __builtin_amdgcn_global_load_lds(
        (const __attribute__((address_space(1))) unsigned int*)(const void*)g,
        (__attribute__((address_space(3))) unsigned int*)(void*)l,
        16, 0, 0);
}

// f32 -> packed (bf16_hi << 16) | bf16_lo  with lo = v - hi
static __device__ __forceinline__ unsigned int packf(float v) {
    __bf16 h = (__bf16)v;
    __bf16 l = (__bf16)(v - (float)h);
    unsigned short hb, lb;
    __builtin_memcpy(&hb, &h, 2);
    __builtin_memcpy(&lb, &l, 2);
    return ((unsigned int)hb << 16) | lb;
}

// ---------------------------------------------------------------------------
// prep 1: wT[j][c] = w_ih[c][j]
// ---------------------------------------------------------------------------
__global__ __launch_bounds__(256) void prep_transpose(const float* __restrict__ w_ih,
                                                      float* __restrict__ wT) {
    int idx = blockIdx.x * 256 + threadIdx.x;       // 128*384
    int j = idx / C3, c = idx % C3;
    wT[idx] = w_ih[c * CDIM + j];
}

// ---------------------------------------------------------------------------
// prep 2: Wc[l][p][c] = sum_j W[l][p][j] * w_ih[c][j]
// ---------------------------------------------------------------------------
__global__ __launch_bounds__(256) void prep_wc(const float* __restrict__ weight,
                                               const float* __restrict__ wT,
                                               float* __restrict__ Wc) {
    __shared__ float wrow[CDIM];
    const int b = blockIdx.x;                        // l*128 + p
    if (threadIdx.x < CDIM) wrow[threadIdx.x] = weight[(size_t)b * CDIM + threadIdx.x];
    __syncthreads();
    for (int c = threadIdx.x; c < C3; c += 256) {
        float acc = 0.f;
        #pragma unroll 8
        for (int j = 0; j < CDIM; ++j) acc = fmaf(wrow[j], wT[j * C3 + c], acc);
        Wc[(size_t)b * C3 + c] = acc;
    }
}

// ---------------------------------------------------------------------------
// prep 3: pack V[256][512] (= [s_r | s_z | i_n | h_n]) into MFMA fragment
// order, bf16 hi/lo.  frag(kt,ct): lane l, j -> V[kt*32+(l>>4)*8+j][ct*16+(l&15)]
// ---------------------------------------------------------------------------
__global__ __launch_bounds__(256) void prep_pack(const float* __restrict__ Wc,
                                                 const float* __restrict__ w_hh,
                                                 __bf16* __restrict__ vfh,
                                                 __bf16* __restrict__ vfl) {
    const int fid  = blockIdx.x * 4 + (threadIdx.x >> 6);   // 0..767 = l*256 + kt*32 + ct
    const int lane = threadIdx.x & 63;
    const int l    = fid >> 8;
    const int rem  = fid & 255;
    const int kt   = rem >> 5, ct = rem & 31;
    const int kbase = kt * 32 + (lane >> 4) * 8;
    const int c     = ct * 16 + (lane & 15);

    bf16x8 H, L;
    #pragma unroll
    for (int j = 0; j < 8; ++j) {
        int k = kbase + j;
        float v;
        if (k < CDIM) {
            v = (c < C3) ? Wc[((size_t)l * CDIM + k) * C3 + c] : 0.f;
        } else {
            int q = k - CDIM;
            if (c < 256)      v = w_hh[(size_t)c * CDIM + q];          // r,z rows
            else if (c < C3)  v = 0.f;                                  // i_n: no h part
            else              v = w_hh[(size_t)(c - CDIM) * CDIM + q];  // n rows 256..383
        }
        __bf16 h = (__bf16)v;
        H[j] = h;
        L[j] = (__bf16)(v - (float)h);
    }
    size_t base = ((size_t)fid * 64 + lane) * 8;
    *(bf16x8*)&vfh[base] = H;
    *(bf16x8*)&vfl[base] = L;
}

// ---------------------------------------------------------------------------
// prep 4: bias4 + zero page
// ---------------------------------------------------------------------------
__global__ void prep_bias(const float* __restrict__ b_ih, const float* __restrict__ b_hh,
                          float* __restrict__ bias4, float* __restrict__ zerob) {
    int c = threadIdx.x;                             // 128 threads
    float4 v = make_float4(b_ih[c] + b_hh[c],
                           b_ih[CDIM + c] + b_hh[CDIM + c],
                           b_ih[256 + c],
                           b_hh[256 + c]);
    *(float4*)&bias4[c * 4] = v;
    zerob[c] = 0.f;
}

// ---------------------------------------------------------------------------
// Fused layer with per-wave double-buffered DMA gather:
//  - eis staged cooperatively; h rows prefetched to regs
//  - wave owns 8 rows; iter i: issue row i+1's 8KB DMA, vmcnt(8), sum row i
//    from wave-private stage (b128 conflict-free), halves via shfl_xor(32)
//  - barrier; reuse stage LDS as swizzled U=[agg|h] bf16 hi/lo tile
//  - MFMA G = U @ V (wave w owns ct = g*8+2w+{0,1} -> gates land in-lane)
//  - in-register GRU epilogue (h from LDS hi+lo) -> hout
// LDS 66KB -> 2 blocks/CU; DMA stays continuously in flight per wave.
// ---------------------------------------------------------------------------
__global__ __launch_bounds__(256, 2) void fused_layer(
        const float* __restrict__ hin, const int* __restrict__ eidx,
        const float* __restrict__ zerob,
        const __bf16* __restrict__ vfh, const __bf16* __restrict__ vfl,
        const float* __restrict__ bias4, float* __restrict__ hout, int N) {
    __shared__ char smem[67584];                     // stage/U 64K | eis 2K
    int* eis = (int*)(smem + 65536);
    const int tid  = threadIdx.x;
    const int wave = tid >> 6, lane = tid & 63;
    const int brow = blockIdx.x * BROWS;

    // ---- stage edge indices (cooperative, int2/thread) ----
    {
        int r = tid >> 3, pq = tid & 7;
        int gr = brow + r;
        int2 v = make_int2(N, N);
        if (gr < N) v = *(const int2*)&eidx[(size_t)gr * 16 + pq * 2];
        *(int2*)&eis[r * 16 + pq * 2] = v;
    }
    __syncthreads();

    // ---- h prefetch into regs (thread = (pr=tid>>3, pcg=tid&7)) ----
    const int pr = tid >> 3, pcg = tid & 7;
    const int pgr = brow + pr;
    float4 hr4[4];
    if (pgr < N) {
        const float4* s = (const float4*)(hin + (size_t)pgr * CDIM + pcg * 16);
        hr4[0] = s[0]; hr4[1] = s[1]; hr4[2] = s[2]; hr4[3] = s[3];
    } else {
        hr4[0] = hr4[1] = hr4[2] = hr4[3] = make_float4(0.f, 0.f, 0.f, 0.f);
    }

    // ---- pipelined DMA gather: 8 rows/wave, dbuf 2 x 8KB ----
    float* stage = (float*)(smem + wave * 16384);    // 4096 floats, wave-private
    const int s31  = lane & 31;
    const int half = lane >> 5;
    float4 areg[8];

    // prologue: issue row 0
    {
        const int* e = &eis[(wave * 8) * 16];
        #pragma unroll
        for (int t = 0; t < 8; ++t) {
            int2 ep = *(const int2*)&e[2 * t];
            int ei = half ? ep.y : ep.x;
            const float* src = ((ei < N) ? (hin + (size_t)ei * CDIM) : zerob) + s31 * 4;
            load_lds16(src, stage + t * 256);
        }
    }
    #pragma unroll
    for (int i = 0; i < 8; ++i) {
        if (i < 7) {
            const int* e = &eis[(wave * 8 + i + 1) * 16];
            float* dst = stage + ((i + 1) & 1) * 2048;
            #pragma unroll
            for (int t = 0; t < 8; ++t) {
                int2 ep = *(const int2*)&e[2 * t];
                int ei = half ? ep.y : ep.x;
                const float* src = ((ei < N) ? (hin + (size_t)ei * CDIM) : zerob) + s31 * 4;
                load_lds16(src, dst + t * 256);
            }
            asm volatile("s_waitcnt vmcnt(8)" ::: "memory");   // row i done, row i+1 in flight
        } else {
            asm volatile("s_waitcnt vmcnt(0)" ::: "memory");
        }
        __builtin_amdgcn_sched_barrier(0);

        const float* buf = stage + (i & 1) * 2048;
        float4 a = make_float4(0.f, 0.f, 0.f, 0.f);
        #pragma unroll
        for (int j = 0; j < 8; ++j) {
            float4 v = *(const float4*)(buf + (half * 8 + j) * 128 + s31 * 4);
            a.x += v.x; a.y += v.y; a.z += v.z; a.w += v.w;
        }
        a.x += __shfl_xor(a.x, 32, 64);
        a.y += __shfl_xor(a.y, 32, 64);
        a.z += __shfl_xor(a.z, 32, 64);
        a.w += __shfl_xor(a.w, 32, 64);
        areg[i] = a;
    }
    __syncthreads();                                 // all stage reads done

    // ---- pack agg (half-0 lanes; row = wave*8+i, cols s31*4) ----
    #pragma unroll
    for (int i = 0; i < 8; ++i) {
        if (lane < 32) {
            int r = wave * 8 + i;
            float4 a = areg[i];
            uint p0 = packf(a.x), p1 = packf(a.y), p2 = packf(a.z), p3 = packf(a.w);
            uint off = (uint)((r * 256 + s31 * 4) * 2) ^ (uint)((r & 7) << 4);
            u16x4 h4 = {(unsigned short)(p0 >> 16), (unsigned short)(p1 >> 16),
                        (unsigned short)(p2 >> 16), (unsigned short)(p3 >> 16)};
            u16x4 l4 = {(unsigned short)(p0 & 0xffff), (unsigned short)(p1 & 0xffff),
                        (unsigned short)(p2 & 0xffff), (unsigned short)(p3 & 0xffff)};
            *(u16x4*)(smem + off)         = h4;
            *(u16x4*)(smem + 16384 + off) = l4;
        }
    }
    // ---- pack h (all threads, from prefetched regs) ----
    #pragma unroll
    for (int i = 0; i < 4; ++i) {
        int col4 = pcg * 16 + i * 4;
        float4 v = hr4[i];
        uint p0 = packf(v.x), p1 = packf(v.y), p2 = packf(v.z), p3 = packf(v.w);
        uint off = (uint)((pr * 256 + 128 + col4) * 2) ^ (uint)((pr & 7) << 4);
        u16x4 h4 = {(unsigned short)(p0 >> 16), (unsigned short)(p1 >> 16),
                    (unsigned short)(p2 >> 16), (unsigned short)(p3 >> 16)};
        u16x4 l4 = {(unsigned short)(p0 & 0xffff), (unsigned short)(p1 & 0xffff),
                    (unsigned short)(p2 & 0xffff), (unsigned short)(p3 & 0xffff)};
        *(u16x4*)(smem + off)         = h4;
        *(u16x4*)(smem + 16384 + off) = l4;
    }
    __syncthreads();

    // ---- MFMA phase: wave w owns ct = g*8 + 2w + {0,1} for all 4 gates ----
    const int lrow = lane & 15, lk = (lane >> 4) * 8;
    f32x4 acc[4][2][2];                              // [gate][j][rt]
    #pragma unroll
    for (int g = 0; g < 4; ++g)
        #pragma unroll
        for (int j = 0; j < 2; ++j)
            #pragma unroll
            for (int rt = 0; rt < 2; ++rt) acc[g][j][rt] = (f32x4){0.f, 0.f, 0.f, 0.f};

    #pragma unroll 1
    for (int kt = 0; kt < 8; ++kt) {
        bf16x8 ah[2], al[2];
        #pragma unroll
        for (int rt = 0; rt < 2; ++rt) {
            int row = rt * 16 + lrow;
            uint off = (uint)((row * 256 + kt * 32 + lk) * 2) ^ (uint)((row & 7) << 4);
            ah[rt] = *(const bf16x8*)(smem + off);
            al[rt] = *(const bf16x8*)(smem + 16384 + off);
        }
        #pragma unroll
        for (int g = 0; g < 4; ++g) {
            if (g == 2 && kt >= 4) continue;         // i_n: only agg K-half
            if (g == 3 && kt < 4)  continue;         // h_n: only h K-half
            #pragma unroll
            for (int j = 0; j < 2; ++j) {
                int ct = g * 8 + 2 * wave + j;
                bf16x8 bh = *(const bf16x8*)(vfh + ((size_t)(kt * 32 + ct) * 64 + lane) * 8);
                bf16x8 bl = *(const bf16x8*)(vfl + ((size_t)(kt * 32 + ct) * 64 + lane) * 8);
                #pragma unroll
                for (int rt = 0; rt < 2; ++rt) {
                    acc[g][j][rt] = mfma16(ah[rt], bh, acc[g][j][rt]);
                    acc[g][j][rt] = mfma16(al[rt], bh, acc[g][j][rt]);
                    acc[g][j][rt] = mfma16(ah[rt], bl, acc[g][j][rt]);
                }
            }
        }
    }

    // ---- in-register epilogue (h reconstructed from LDS hi+lo) ----
    const int q = lane >> 4;
    #pragma unroll
    for (int j = 0; j < 2; ++j) {
        int c = 32 * wave + j * 16 + lrow;
        float4 b = *(const float4*)&bias4[c * 4];
        #pragma unroll
        for (int rt = 0; rt < 2; ++rt) {
            #pragma unroll
            for (int reg = 0; reg < 4; ++reg) {
                int n  = rt * 16 + q * 4 + reg;
                int gr = brow + n;
                float rv = acc[0][j][rt][reg] + b.x;
                float zv = acc[1][j][rt][reg] + b.y;
                float nv = acc[2][j][rt][reg] + b.z;
                float hv = acc[3][j][rt][reg] + b.w;
                float rr = 1.f / (1.f + __expf(-rv));
                float zz = 1.f / (1.f + __expf(-zv));
                float nn = tanhf(nv + rr * hv);
                uint off = (uint)((n * 256 + 128 + c) * 2) ^ (uint)((n & 7) << 4);
                unsigned short hb = *(const unsigned short*)(smem + off);
                unsigned short lb = *(const unsigned short*)(smem + 16384 + off);
                float h = __uint_as_float((uint)hb << 16) + __uint_as_float((uint)lb << 16);
                if (gr < N)
                    hout[(size_t)gr * CDIM + c] = (1.f - zz) * nn + zz * h;
            }
        }
    }
}

// ---------------------------------------------------------------------------
extern "C" void kernel_launch(void* const* d_in, const int* in_sizes, int n_in,
                              void* d_out, int out_size, void* d_ws, size_t ws_size,
                              hipStream_t stream) {
    const float* x      = (const float*)d_in[0];
    const int*   eidx   = (const int*)  d_in[1];
    const float* weight = (const float*)d_in[2];
    const float* w_ih   = (const float*)d_in[3];
    const float* w_hh   = (const float*)d_in[4];
    const float* b_ih   = (const float*)d_in[5];
    const float* b_hh   = (const float*)d_in[6];
    float* out = (float*)d_out;

    const int N = in_sizes[0] / CDIM;

    char* p = (char*)d_ws;
    float*  bufA  = (float*)p;  p += (size_t)N * CDIM * 4;
    float*  Wc    = (float*)p;  p += (size_t)NLAYER * CDIM * C3 * 4;
    float*  wT    = (float*)p;  p += (size_t)CDIM * C3 * 4;
    float*  bias4 = (float*)p;  p += 512 * 4;
    float*  zerob = (float*)p;  p += CDIM * 4;
    __bf16* vfh   = (__bf16*)p; p += (size_t)NLAYER * 131072 * 2;
    __bf16* vfl   = (__bf16*)p;

    prep_transpose<<<192, 256, 0, stream>>>(w_ih, wT);
    prep_wc<<<NLAYER * CDIM, 256, 0, stream>>>(weight, wT, Wc);
    prep_pack<<<192, 256, 0, stream>>>(Wc, w_hh, vfh, vfl);
    prep_bias<<<1, 128, 0, stream>>>(b_ih, b_hh, bias4, zerob);

    const int nb = (N + BROWS - 1) / BROWS;
    const size_t VSZ = 131072;
    fused_layer<<<nb, 256, 0, stream>>>(x,    eidx, zerob, vfh,           vfl,           bias4, out,  N);
    fused_layer<<<nb, 256, 0, stream>>>(out,  eidx, zerob, vfh + VSZ,     vfl + VSZ,     bias4, bufA, N);
    fused_layer<<<nb, 256, 0, stream>>>(bufA, eidx, zerob, vfh + 2 * VSZ, vfl + 2 * VSZ, bias4, out,  N);
}

// Round 9
// 585.472 us; speedup vs baseline: 1.5260x; 1.4095x over previous
//
#include <hip/hip_runtime.h>

#define CDIM 128
#define C3   384
#define NLAYER 3
#define BROWS 32     // rows per fused block

typedef __attribute__((ext_vector_type(8))) __bf16 bf16x8;
typedef __attribute__((ext_vector_type(4))) float  f32x4;
typedef __attribute__((ext_vector_type(4))) unsigned short u16x4;

static __device__ __forceinline__ f32x4 mfma16(bf16x8 a, bf16x8 b, f32x4 c) {
    return __builtin_amdgcn_mfma_f32_16x16x32_bf16(a, b, c, 0, 0, 0);
}

// f32 -> packed (bf16_hi << 16) | bf16_lo  with lo = v - hi
static __device__ __forceinline__ unsigned int packf(float v) {
    __bf16 h = (__bf16)v;
    __bf16 l = (__bf16)(v - (float)h);
    unsigned short hb, lb;
    __builtin_memcpy(&hb, &h, 2);
    __builtin_memcpy(&lb, &l, 2);
    return ((unsigned int)hb << 16) | lb;
}

// ---------------------------------------------------------------------------
// prep 1: wT[j][c] = w_ih[c][j]
// ---------------------------------------------------------------------------
__global__ __launch_bounds__(256) void prep_transpose(const float* __restrict__ w_ih,
                                                      float* __restrict__ wT) {
    int idx = blockIdx.x * 256 + threadIdx.x;       // 128*384
    int j = idx / C3, c = idx % C3;
    wT[idx] = w_ih[c * CDIM + j];
}

// ---------------------------------------------------------------------------
// prep 2: Wc[l][p][c] = sum_j W[l][p][j] * w_ih[c][j]
// ---------------------------------------------------------------------------
__global__ __launch_bounds__(256) void prep_wc(const float* __restrict__ weight,
                                               const float* __restrict__ wT,
                                               float* __restrict__ Wc) {
    __shared__ float wrow[CDIM];
    const int b = blockIdx.x;                        // l*128 + p
    if (threadIdx.x < CDIM) wrow[threadIdx.x] = weight[(size_t)b * CDIM + threadIdx.x];
    __syncthreads();
    for (int c = threadIdx.x; c < C3; c += 256) {
        float acc = 0.f;
        #pragma unroll 8
        for (int j = 0; j < CDIM; ++j) acc = fmaf(wrow[j], wT[j * C3 + c], acc);
        Wc[(size_t)b * C3 + c] = acc;
    }
}

// ---------------------------------------------------------------------------
// prep 3: pack V[256][512] (= [s_r | s_z | i_n | h_n]) into MFMA fragment
// order, bf16 hi/lo.  frag(kt,ct): lane l, j -> V[kt*32+(l>>4)*8+j][ct*16+(l&15)]
// ---------------------------------------------------------------------------
__global__ __launch_bounds__(256) void prep_pack(const float* __restrict__ Wc,
                                                 const float* __restrict__ w_hh,
                                                 __bf16* __restrict__ vfh,
                                                 __bf16* __restrict__ vfl) {
    const int fid  = blockIdx.x * 4 + (threadIdx.x >> 6);   // 0..767 = l*256 + kt*32 + ct
    const int lane = threadIdx.x & 63;
    const int l    = fid >> 8;
    const int rem  = fid & 255;
    const int kt   = rem >> 5, ct = rem & 31;
    const int kbase = kt * 32 + (lane >> 4) * 8;
    const int c     = ct * 16 + (lane & 15);

    bf16x8 H, L;
    #pragma unroll
    for (int j = 0; j < 8; ++j) {
        int k = kbase + j;
        float v;
        if (k < CDIM) {
            v = (c < C3) ? Wc[((size_t)l * CDIM + k) * C3 + c] : 0.f;
        } else {
            int q = k - CDIM;
            if (c < 256)      v = w_hh[(size_t)c * CDIM + q];          // r,z rows
            else if (c < C3)  v = 0.f;                                  // i_n: no h part
            else              v = w_hh[(size_t)(c - CDIM) * CDIM + q];  // n rows 256..383
        }
        __bf16 h = (__bf16)v;
        H[j] = h;
        L[j] = (__bf16)(v - (float)h);
    }
    size_t base = ((size_t)fid * 64 + lane) * 8;
    *(bf16x8*)&vfh[base] = H;
    *(bf16x8*)&vfl[base] = L;
}

// ---------------------------------------------------------------------------
// prep 4: bias4
// ---------------------------------------------------------------------------
__global__ void prep_bias(const float* __restrict__ b_ih, const float* __restrict__ b_hh,
                          float* __restrict__ bias4) {
    int c = threadIdx.x;                             // 128 threads
    float4 v = make_float4(b_ih[c] + b_hh[c],
                           b_ih[CDIM + c] + b_hh[CDIM + c],
                           b_ih[256 + c],
                           b_hh[256 + c]);
    *(float4*)&bias4[c * 4] = v;
}

// ---------------------------------------------------------------------------
// Fused layer, register gather @ 4 blocks/CU:
//  - eidx staged in LDS
//  - 4 iterations of task (r = t>>5, c4 = (t&31)*4): lanes 0-31 cover one
//    neighbor row contiguously; 16 masked float4 loads accumulate agg in
//    VGPRs; h float4 loaded in the same window; both packed bf16 hi/lo into
//    the swizzled U=[agg|h] tile
//  - MFMA G = U @ V (wave w owns ct = g*8+2w+{0,1} -> 4 gates land in-lane)
//  - in-register GRU epilogue (h from LDS hi+lo) -> hout
// LDS 34.8KB -> 4 blocks/CU; co-resident blocks at different phases overlap
// gather (VMEM) with MFMA/pack (LDS/MATRIX pipes).
// ---------------------------------------------------------------------------
__global__ __launch_bounds__(256, 4) void fused_layer(
        const float* __restrict__ hin, const int* __restrict__ eidx,
        const __bf16* __restrict__ vfh, const __bf16* __restrict__ vfl,
        const float* __restrict__ bias4, float* __restrict__ hout, int N) {
    __shared__ char smem[34816];                     // U hi 16K | U lo 16K | eis 2K
    int* eis = (int*)(smem + 32768);
    const int tid  = threadIdx.x;
    const int brow = blockIdx.x * BROWS;

    // ---- stage edge indices (cooperative, int2/thread) ----
    {
        int r = tid >> 3, pq = tid & 7;
        int gr = brow + r;
        int2 v = make_int2(N, N);
        if (gr < N) v = *(const int2*)&eidx[(size_t)gr * 16 + pq * 2];
        *(int2*)&eis[r * 16 + pq * 2] = v;
    }
    __syncthreads();

    // ---- register gather + h load + U pack (coalesced: 32 lanes = 1 row) ----
    #pragma unroll 1
    for (int it = 0; it < 4; ++it) {
        const int t  = tid + it * 256;
        const int r  = t >> 5;                       // 0..31
        const int c4 = (t & 31) << 2;                // float col offset
        const int gr = brow + r;

        float4 hv = make_float4(0.f, 0.f, 0.f, 0.f);
        if (gr < N) hv = *(const float4*)&hin[(size_t)gr * CDIM + c4];

        const int* e = &eis[r * 16];
        float4 a = make_float4(0.f, 0.f, 0.f, 0.f);
        #pragma unroll
        for (int k = 0; k < 16; ++k) {
            int ei = e[k];
            float msk = (ei < N) ? 1.f : 0.f;
            int   ci  = (ei < N) ? ei : 0;
            const float4 v = *(const float4*)&hin[(size_t)ci * CDIM + c4];
            a.x = fmaf(v.x, msk, a.x);
            a.y = fmaf(v.y, msk, a.y);
            a.z = fmaf(v.z, msk, a.z);
            a.w = fmaf(v.w, msk, a.w);
        }

        {   // agg at (r, c4)
            uint p0 = packf(a.x), p1 = packf(a.y), p2 = packf(a.z), p3 = packf(a.w);
            uint off = (uint)((r * 256 + c4) * 2) ^ (uint)((r & 7) << 4);
            u16x4 h4 = {(unsigned short)(p0 >> 16), (unsigned short)(p1 >> 16),
                        (unsigned short)(p2 >> 16), (unsigned short)(p3 >> 16)};
            u16x4 l4 = {(unsigned short)(p0 & 0xffff), (unsigned short)(p1 & 0xffff),
                        (unsigned short)(p2 & 0xffff), (unsigned short)(p3 & 0xffff)};
            *(u16x4*)(smem + off)         = h4;
            *(u16x4*)(smem + 16384 + off) = l4;
        }
        {   // h at (r, 128+c4)
            uint p0 = packf(hv.x), p1 = packf(hv.y), p2 = packf(hv.z), p3 = packf(hv.w);
            uint off = (uint)((r * 256 + 128 + c4) * 2) ^ (uint)((r & 7) << 4);
            u16x4 h4 = {(unsigned short)(p0 >> 16), (unsigned short)(p1 >> 16),
                        (unsigned short)(p2 >> 16), (unsigned short)(p3 >> 16)};
            u16x4 l4 = {(unsigned short)(p0 & 0xffff), (unsigned short)(p1 & 0xffff),
                        (unsigned short)(p2 & 0xffff), (unsigned short)(p3 & 0xffff)};
            *(u16x4*)(smem + off)         = h4;
            *(u16x4*)(smem + 16384 + off) = l4;
        }
    }
    __syncthreads();

    // ---- MFMA phase: wave w owns ct = g*8 + 2w + {0,1} for all 4 gates ----
    const int wave = tid >> 6, lane = tid & 63;
    const int lrow = lane & 15, lk = (lane >> 4) * 8;
    f32x4 acc[4][2][2];                              // [gate][j][rt]
    #pragma unroll
    for (int g = 0; g < 4; ++g)
        #pragma unroll
        for (int j = 0; j < 2; ++j)
            #pragma unroll
            for (int rt = 0; rt < 2; ++rt) acc[g][j][rt] = (f32x4){0.f, 0.f, 0.f, 0.f};

    #pragma unroll 1
    for (int kt = 0; kt < 8; ++kt) {
        bf16x8 ah[2], al[2];
        #pragma unroll
        for (int rt = 0; rt < 2; ++rt) {
            int row = rt * 16 + lrow;
            uint off = (uint)((row * 256 + kt * 32 + lk) * 2) ^ (uint)((row & 7) << 4);
            ah[rt] = *(const bf16x8*)(smem + off);
            al[rt] = *(const bf16x8*)(smem + 16384 + off);
        }
        #pragma unroll
        for (int g = 0; g < 4; ++g) {
            if (g == 2 && kt >= 4) continue;         // i_n: only agg K-half
            if (g == 3 && kt < 4)  continue;         // h_n: only h K-half
            #pragma unroll
            for (int j = 0; j < 2; ++j) {
                int ct = g * 8 + 2 * wave + j;
                bf16x8 bh = *(const bf16x8*)(vfh + ((size_t)(kt * 32 + ct) * 64 + lane) * 8);
                bf16x8 bl = *(const bf16x8*)(vfl + ((size_t)(kt * 32 + ct) * 64 + lane) * 8);
                #pragma unroll
                for (int rt = 0; rt < 2; ++rt) {
                    acc[g][j][rt] = mfma16(ah[rt], bh, acc[g][j][rt]);
                    acc[g][j][rt] = mfma16(al[rt], bh, acc[g][j][rt]);
                    acc[g][j][rt] = mfma16(ah[rt], bl, acc[g][j][rt]);
                }
            }
        }
    }

    // ---- in-register epilogue (h reconstructed from LDS hi+lo) ----
    const int q = lane >> 4;
    #pragma unroll
    for (int j = 0; j < 2; ++j) {
        int c = 32 * wave + j * 16 + lrow;
        float4 b = *(const float4*)&bias4[c * 4];
        #pragma unroll
        for (int rt = 0; rt < 2; ++rt) {
            #pragma unroll
            for (int reg = 0; reg < 4; ++reg) {
                int n  = rt * 16 + q * 4 + reg;
                int gr = brow + n;
                float rv = acc[0][j][rt][reg] + b.x;
                float zv = acc[1][j][rt][reg] + b.y;
                float nv = acc[2][j][rt][reg] + b.z;
                float hv = acc[3][j][rt][reg] + b.w;
                float rr = 1.f / (1.f + __expf(-rv));
                float zz = 1.f / (1.f + __expf(-zv));
                float nn = tanhf(nv + rr * hv);
                uint off = (uint)((n * 256 + 128 + c) * 2) ^ (uint)((n & 7) << 4);
                unsigned short hb = *(const unsigned short*)(smem + off);
                unsigned short lb = *(const unsigned short*)(smem + 16384 + off);
                float h = __uint_as_float((uint)hb << 16) + __uint_as_float((uint)lb << 16);
                if (gr < N)
                    hout[(size_t)gr * CDIM + c] = (1.f - zz) * nn + zz * h;
            }
        }
    }
}

// ---------------------------------------------------------------------------
extern "C" void kernel_launch(void* const* d_in, const int* in_sizes, int n_in,
                              void* d_out, int out_size, void* d_ws, size_t ws_size,
                              hipStream_t stream) {
    const float* x      = (const float*)d_in[0];
    const int*   eidx   = (const int*)  d_in[1];
    const float* weight = (const float*)d_in[2];
    const float* w_ih   = (const float*)d_in[3];
    const float* w_hh   = (const float*)d_in[4];
    const float* b_ih   = (const float*)d_in[5];
    const float* b_hh   = (const float*)d_in[6];
    float* out = (float*)d_out;

    const int N = in_sizes[0] / CDIM;

    char* p = (char*)d_ws;
    float*  bufA  = (float*)p;  p += (size_t)N * CDIM * 4;
    float*  Wc    = (float*)p;  p += (size_t)NLAYER * CDIM * C3 * 4;
    float*  wT    = (float*)p;  p += (size_t)CDIM * C3 * 4;
    float*  bias4 = (float*)p;  p += 512 * 4;
    __bf16* vfh   = (__bf16*)p; p += (size_t)NLAYER * 131072 * 2;
    __bf16* vfl   = (__bf16*)p;

    prep_transpose<<<192, 256, 0, stream>>>(w_ih, wT);
    prep_wc<<<NLAYER * CDIM, 256, 0, stream>>>(weight, wT, Wc);
    prep_pack<<<192, 256, 0, stream>>>(Wc, w_hh, vfh, vfl);
    prep_bias<<<1, 128, 0, stream>>>(b_ih, b_hh, bias4);

    const int nb = (N + BROWS - 1) / BROWS;
    const size_t VSZ = 131072;
    // ping-pong buffers: no in-place gather races
    fused_layer<<<nb, 256, 0, stream>>>(x,    eidx, vfh,           vfl,           bias4, out,  N);
    fused_layer<<<nb, 256, 0, stream>>>(out,  eidx, vfh + VSZ,     vfl + VSZ,     bias4, bufA, N);
    fused_layer<<<nb, 256, 0, stream>>>(bufA, eidx, vfh + 2 * VSZ, vfl + 2 * VSZ, bias4, out,  N);
}